// Round 3
// baseline (1621.312 us; speedup 1.0000x reference)
//
#include <hip/hip_runtime.h>
#include <stdint.h>
#include <string.h>

#define BB 256
#define TT 2048
#define DD 64

typedef __fp16 f16x8 __attribute__((ext_vector_type(8)));
typedef float  f32x4 __attribute__((ext_vector_type(4)));

#define C_L2E 1.44269504f
#define C_LN2 0.69314718f

__device__ __forceinline__ int pki(float a, float b) {
    auto pk = __builtin_amdgcn_cvt_pkrtz(a, b);   // RTZ pack: overflow saturates to max-finite
    int r; __builtin_memcpy(&r, &pk, 4); return r;
}
__device__ __forceinline__ float expf_fast(float x) {
    return __builtin_amdgcn_exp2f(x * C_L2E);
}

union PK { int i[4]; f16x8 h; };

// ---------------- kernel 1: lengths + emission/transition scores (parallel, mem-bound) ----------
__global__ __launch_bounds__(256) void crf_score(
    const float* __restrict__ p, const int* __restrict__ y,
    const int* __restrict__ mask, const float* __restrict__ tr,
    int* __restrict__ wsL, float* __restrict__ wsS)
{
    __shared__ int   labs[TT];
    __shared__ int   redi[4];
    __shared__ float redf[4];
    __shared__ int   Lsh;
    const int c   = blockIdx.x;
    const int tid = threadIdx.x;

    int cnt = 0;
    for (int t = tid; t < TT; t += 256) cnt += (mask[c * TT + t] == 0) ? 1 : 0;
#pragma unroll
    for (int xm = 32; xm >= 1; xm >>= 1) cnt += __shfl_xor(cnt, xm, 64);
    if ((tid & 63) == 0) redi[tid >> 6] = cnt;
    __syncthreads();
    if (tid == 0) { Lsh = redi[0] + redi[1] + redi[2] + redi[3]; wsL[c] = Lsh; }
    __syncthreads();
    const int L = Lsh;

    const int w = tid >> 6, e = tid & 63;
    float s1 = 0.f;
    for (int t = w; t < L; t += 4) {              // only valid prefix needed
        float pv = p[((size_t)c * TT + t) * DD + e];
        int   yv = y[((size_t)c * TT + t) * DD + e];
        unsigned long long bal = __ballot(yv != 0);
        int lab = (int)__builtin_ctzll(bal);
        if (e == 0) labs[t] = lab;
        if (yv != 0) s1 += pv;
    }
    __syncthreads();
    float s2 = 0.f;
    for (int t = tid; t < L - 1; t += 256)
        s2 += tr[labs[t] * DD + labs[t + 1]];
    float acc = s1 + s2;
#pragma unroll
    for (int xm = 32; xm >= 1; xm >>= 1) acc += __shfl_xor(acc, xm, 64);
    if ((tid & 63) == 0) redf[tid >> 6] = acc;
    __syncthreads();
    if (tid == 0) wsS[c] = redf[0] + redf[1] + redf[2] + redf[3];
}

// ---------------- kernel 2: MFMA-batched forward recurrence -------------------------------------
// Block cb handles chains 16cb..16cb+15. Wave1 = producer: E_t = exp(p_t) into 16-slot LDS ring.
// Wave0 = consumer: per step  v = u*W (8x mfma 16x16x32 f16, A=W^T resident),
//   u' = pkrtz(v * E'_t) with E'_t = E_t * 2^-k_{t-1}; a0 += k_{t-1}*ln2.
// State labeling: e = 16q + 4g + r (C-layout), d = 16q + 8f + j (B-layout) -> no cross-lane moves.
__global__ __launch_bounds__(128) void crf_forward(
    const float* __restrict__ p, const float* __restrict__ tr,
    const int* __restrict__ wsL, const float* __restrict__ wsS,
    float* __restrict__ out)
{
    __shared__ float ering[16 * 1024];   // 16 slots x 64 lanes x 16 floats = 64 KB
    const int cb  = blockIdx.x;
    const int tid = threadIdx.x;
    const int wv  = tid >> 6;
    const int l   = tid & 63;
    const int ml  = l & 15;   // chain within block
    const int q   = l >> 4;

    // bank-swizzled chunk offsets (floats) within a slot: lane l chunk j
    int wa[4];
#pragma unroll
    for (int j = 0; j < 4; ++j) wa[j] = l * 16 + ((j + (l >> 1)) & 3) * 4;

    // ---------- producer state ----------
    const float* psrc = p + ((size_t)(cb * 16 + ml) * TT) * DD + 16 * q;

    // ---------- consumer state ----------
    f16x8 Af[2][4];
    PK ub0, ub1, sn0, sn1;
    float Ep[16];
    float a0 = 0.f, a0snap = 0.f, scv = 0.f;
    int kprev = 0, Lcm1 = 0;
    const int idxb = ml * 4;
    const f32x4 z4 = {0.f, 0.f, 0.f, 0.f};
#pragma unroll
    for (int k2 = 0; k2 < 4; ++k2) { ub0.i[k2] = 0; ub1.i[k2] = 0; sn0.i[k2] = 0; sn1.i[k2] = 0; }
#pragma unroll
    for (int i = 0; i < 16; ++i) Ep[i] = 0.f;

    auto fill = [&](int t) {
        const f32x4* p4 = (const f32x4*)(psrc + (size_t)t * DD);
        f32x4 in[4];
#pragma unroll
        for (int j = 0; j < 4; ++j) in[j] = p4[j];
        const int sb = (t & 15) * 1024;
#pragma unroll
        for (int j = 0; j < 4; ++j) {
            f32x4 ex;
            ex[0] = expf_fast(in[j][0]); ex[1] = expf_fast(in[j][1]);
            ex[2] = expf_fast(in[j][2]); ex[3] = expf_fast(in[j][3]);
            *(f32x4*)(ering + sb + wa[j]) = ex;
        }
    };
    auto rdslot = [&](int st, float* dst) {
        const int sb = (st & 15) * 1024;
#pragma unroll
        for (int j = 0; j < 4; ++j) {
            f32x4 v = *(const f32x4*)(ering + sb + wa[j]);
            dst[4 * j + 0] = v[0]; dst[4 * j + 1] = v[1];
            dst[4 * j + 2] = v[2]; dst[4 * j + 3] = v[3];
        }
    };

    if (wv == 1) {
        for (int t = 0; t < 8; ++t) fill(t);   // pre-fill slots 0..7
    } else {
        Lcm1 = wsL[cb * 16 + ml] - 1;
        scv  = wsS[cb * 16 + ml];
        // A = W^T fragments, permuted labeling; resident for whole kernel
#pragma unroll
        for (int f = 0; f < 2; ++f)
#pragma unroll
            for (int g = 0; g < 4; ++g)
#pragma unroll
                for (int jj = 0; jj < 8; ++jj) {
                    int d = 16 * q + 8 * f + jj;
                    int e = 16 * (ml >> 2) + 4 * g + (ml & 3);
                    Af[f][g][jj] = (__fp16)expf_fast(tr[d * DD + e]);
                }
    }

    for (int n = 1; n <= 256; ++n) {
        __syncthreads();   // slots [8(n-1) .. 8n) now valid for consumer
        if (wv == 1) {
            const int tb = 8 * n;
#pragma unroll
            for (int j = 0; j < 8; ++j) { int t = tb + j; if (t < TT) fill(t); }
        } else {
            const int sbase = 8 * (n - 1);
            int jstart = 0;
            if (n == 1) {
                // init: alpha_0 = p_0  ->  u_0 = E_0 * 2^-k0 (wait for broadcast at init only)
                float xr[16];
                rdslot(0, xr);
                int kc = ((__float_as_int(xr[0]) >> 23) & 255) - 126;
                int kb = __builtin_amdgcn_ds_bpermute(idxb, kc);
                kb = kb < -120 ? -120 : (kb > 120 ? 120 : kb);
                float sc_ = __int_as_float((127 - kb) << 23);
#pragma unroll
                for (int i = 0; i < 16; ++i) xr[i] *= sc_;
                ub0.i[0] = pki(xr[0], xr[1]);  ub0.i[1] = pki(xr[2], xr[3]);
                ub0.i[2] = pki(xr[4], xr[5]);  ub0.i[3] = pki(xr[6], xr[7]);
                ub1.i[0] = pki(xr[8], xr[9]);  ub1.i[1] = pki(xr[10], xr[11]);
                ub1.i[2] = pki(xr[12], xr[13]); ub1.i[3] = pki(xr[14], xr[15]);
                a0 = (float)kb * C_LN2;
                kprev = kb;
                float er[16];
                rdslot(1, er);
                float sc2 = __int_as_float((127 - kprev) << 23);
#pragma unroll
                for (int i = 0; i < 16; ++i) Ep[i] = er[i] * sc2;
                jstart = 1;
            } else {
                float er[16];
                rdslot(sbase, er);   // prescale E for step sbase with k from previous step
                float sc2 = __int_as_float((127 - kprev) << 23);
#pragma unroll
                for (int i = 0; i < 16; ++i) Ep[i] = er[i] * sc2;
            }
#pragma unroll
            for (int j = 0; j < 8; ++j) {
                if (j < jstart) continue;
                const int s = sbase + j;
                f32x4 v[4];
#pragma unroll
                for (int g = 0; g < 4; ++g)
                    v[g] = __builtin_amdgcn_mfma_f32_16x16x32_f16(Af[0][g], ub0.h, z4, 0, 0, 0);
#pragma unroll
                for (int g = 0; g < 4; ++g)
                    v[g] = __builtin_amdgcn_mfma_f32_16x16x32_f16(Af[1][g], ub1.h, v[g], 0, 0, 0);
                float er[16];
                if (j < 7) rdslot(s + 1, er);            // issue early; latency hidden
                a0 += (float)kprev * C_LN2;
                float x[16];
#pragma unroll
                for (int g = 0; g < 4; ++g) {
                    x[4 * g + 0] = v[g][0] * Ep[4 * g + 0];
                    x[4 * g + 1] = v[g][1] * Ep[4 * g + 1];
                    x[4 * g + 2] = v[g][2] * Ep[4 * g + 2];
                    x[4 * g + 3] = v[g][3] * Ep[4 * g + 3];
                }
                int kc = ((__float_as_int(x[0]) >> 23) & 255) - 126;   // exponent of state-0 value
                int kb = __builtin_amdgcn_ds_bpermute(idxb, kc);       // broadcast within chain column
                ub0.i[0] = pki(x[0], x[1]);   ub0.i[1] = pki(x[2], x[3]);
                ub0.i[2] = pki(x[4], x[5]);   ub0.i[3] = pki(x[6], x[7]);
                ub1.i[0] = pki(x[8], x[9]);   ub1.i[1] = pki(x[10], x[11]);
                ub1.i[2] = pki(x[12], x[13]); ub1.i[3] = pki(x[14], x[15]);
                const bool hit = (s == Lcm1);
#pragma unroll
                for (int k2 = 0; k2 < 4; ++k2) {
                    sn0.i[k2] = hit ? ub0.i[k2] : sn0.i[k2];
                    sn1.i[k2] = hit ? ub1.i[k2] : sn1.i[k2];
                }
                a0snap = hit ? a0 : a0snap;
                kb = kb < -120 ? -120 : (kb > 120 ? 120 : kb);
                kprev = kb;
                if (j < 7) {
                    float sc2 = __int_as_float((127 - kprev) << 23);
#pragma unroll
                    for (int i = 0; i < 16; ++i) Ep[i] = er[i] * sc2;
                }
            }
        }
    }

    if (wv == 0) {
        float ssum = 0.f;
#pragma unroll
        for (int k2 = 0; k2 < 4; ++k2) {
            __fp16 h2a[2];
            __builtin_memcpy(h2a, &sn0.i[k2], 4);
            ssum += (float)h2a[0] + (float)h2a[1];
            __builtin_memcpy(h2a, &sn1.i[k2], 4);
            ssum += (float)h2a[0] + (float)h2a[1];
        }
        ssum += __shfl_xor(ssum, 16, 64);
        ssum += __shfl_xor(ssum, 32, 64);
        float logZ = a0snap + C_LN2 * __builtin_amdgcn_logf(ssum);
        if (q == 0) out[cb * 16 + ml] = logZ - scv;
    }
}

extern "C" void kernel_launch(void* const* d_in, const int* in_sizes, int n_in,
                              void* d_out, int out_size, void* d_ws, size_t ws_size,
                              hipStream_t stream) {
    const float* p  = (const float*)d_in[0];
    const int*   y  = (const int*)d_in[1];
    const int*   mk = (const int*)d_in[2];
    const float* tr = (const float*)d_in[3];
    float* out = (float*)d_out;
    int*   wsL = (int*)d_ws;
    float* wsS = (float*)((char*)d_ws + 1024);
    crf_score<<<dim3(BB), dim3(256), 0, stream>>>(p, y, mk, tr, wsL, wsS);
    crf_forward<<<dim3(BB / 16), dim3(128), 0, stream>>>(p, tr, wsL, wsS, out);
}

// Round 5
// 538.398 us; speedup vs baseline: 3.0114x; 3.0114x over previous
//
#include <hip/hip_runtime.h>
#include <stdint.h>
#include <string.h>

#define BB 256
#define TT 2048
#define DD 64
#define C_L2E 1.44269504f
#define C_LN2 0.69314718f

typedef short sh8  __attribute__((ext_vector_type(8)));
typedef float f32x4 __attribute__((ext_vector_type(4)));

__device__ __forceinline__ float expf_fast(float x) { return __builtin_amdgcn_exp2f(x * C_L2E); }
__device__ __forceinline__ unsigned short bf16rne(float x) {
    unsigned int u = __float_as_uint(x);
    u += 0x7FFF + ((u >> 16) & 1u);
    return (unsigned short)(u >> 16);
}

#define DPPMAX(x, ctrl, rm, bm) { int _xi = __float_as_int(x);                              \
    int _yi = __builtin_amdgcn_update_dpp(_xi, _xi, ctrl, rm, bm, false);                   \
    x = fmaxf(x, __int_as_float(_yi)); }

// ---------- kernel 1: lengths + emission/transition scores (parallel) ----------
__global__ __launch_bounds__(256) void crf_score(
    const float* __restrict__ p, const int* __restrict__ y,
    const int* __restrict__ mask, const float* __restrict__ tr,
    int* __restrict__ wsL, float* __restrict__ wsS)
{
    __shared__ unsigned short labs[TT];
    __shared__ int   redi[4];
    __shared__ float redf[4];
    __shared__ int   Lsh;
    const int c = blockIdx.x, tid = threadIdx.x;

    const int4* m4 = (const int4*)(mask + (size_t)c * TT);
    int4 ma = m4[tid * 2], mb = m4[tid * 2 + 1];
    int cnt = (ma.x == 0) + (ma.y == 0) + (ma.z == 0) + (ma.w == 0)
            + (mb.x == 0) + (mb.y == 0) + (mb.z == 0) + (mb.w == 0);
#pragma unroll
    for (int xm = 32; xm >= 1; xm >>= 1) cnt += __shfl_xor(cnt, xm, 64);
    if ((tid & 63) == 0) redi[tid >> 6] = cnt;
    __syncthreads();
    if (tid == 0) { Lsh = redi[0] + redi[1] + redi[2] + redi[3]; wsL[c] = Lsh; }
    __syncthreads();
    const int L = Lsh;

    float s1 = 0.f;
#pragma unroll
    for (int rep = 0; rep < 8; ++rep) {
        int t = rep * 256 + tid;
        if (t < L) {
            const int4* yt = (const int4*)(y) + ((size_t)c * TT + t) * 16;
            int lab = 0;
#pragma unroll
            for (int g = 0; g < 16; ++g) {
                int4 v = yt[g];
                if (v.x) lab = 4 * g;     if (v.y) lab = 4 * g + 1;
                if (v.z) lab = 4 * g + 2; if (v.w) lab = 4 * g + 3;
            }
            labs[t] = (unsigned short)lab;
            s1 += p[((size_t)c * TT + t) * DD + lab];
        }
    }
    __syncthreads();
    float s2 = 0.f;
#pragma unroll
    for (int rep = 0; rep < 8; ++rep) {
        int t = rep * 256 + tid;
        if (t < L - 1) s2 += tr[(int)labs[t] * DD + (int)labs[t + 1]];
    }
    float acc = s1 + s2;
#pragma unroll
    for (int xm = 32; xm >= 1; xm >>= 1) acc += __shfl_xor(acc, xm, 64);
    if ((tid & 63) == 0) redf[tid >> 6] = acc;
    __syncthreads();
    if (tid == 0) wsS[c] = redf[0] + redf[1] + redf[2] + redf[3];
}

// ---------- kernel 2: chunk transfer matrices H = prod_t diag(e_t) W^T  (bf16 MFMA) ----------
// Physical layouts (HW-verified): A[m=lane&15][k=8*(lane>>4)+j]; B[k=8*(lane>>4)+j][n=lane&15];
// D row = 16mt + 4*(lane>>4) + reg, col = lane&15.
// Contraction relabeling lam(kt2,j,q) = 32kt2 + 16(j>>2) + 4q + (j&3) makes D->B in-lane:
// B[kt2][nt].j <- D[mt=2kt2+(j>>2)][nt].reg=(j&3), and lam == natural D row.
union BU { sh8 v8; unsigned int u[4]; unsigned short s[8]; };

__global__ __launch_bounds__(128, 2) void crf_chunk(
    const float* __restrict__ p, const float* __restrict__ tr,
    const int* __restrict__ wsL, unsigned short* __restrict__ wsH, int* __restrict__ wsK,
    int C, int S)
{
    __shared__ float E[128 * 64];   // 32 KB staging window (128 timesteps)
    const int c = blockIdx.x, ic = blockIdx.y;
    const int t0 = ic * S, t1 = t0 + S;
    const int L = wsL[c];
    const int tid = threadIdx.x, w = tid >> 6, lane = tid & 63;
    const int q = lane >> 4, ml = lane & 15;

    // A = W^T resident: A[mt][kt2].s[j] = bf16(exp(T[lam][16mt+ml]))
    BU A[4][2];
#pragma unroll
    for (int mt = 0; mt < 4; ++mt)
#pragma unroll
        for (int kt2 = 0; kt2 < 2; ++kt2)
#pragma unroll
            for (int j = 0; j < 8; ++j) {
                int lam = 32 * kt2 + 16 * (j >> 2) + 4 * q + (j & 3);
                A[mt][kt2].s[j] = (short)bf16rne(expf_fast(tr[lam * DD + 16 * mt + ml]));
            }

    // B init = identity
    BU Bf[2][2];
#pragma unroll
    for (int kt2 = 0; kt2 < 2; ++kt2)
#pragma unroll
        for (int nt = 0; nt < 2; ++nt)
#pragma unroll
            for (int j = 0; j < 8; ++j) {
                int lam = 32 * kt2 + 16 * (j >> 2) + 4 * q + (j & 3);
                int col = 32 * w + 16 * nt + ml;
                Bf[kt2][nt].s[j] = (short)((lam == col) ? 0x3F80 : 0);
            }

    int sig = 0;
    const f32x4 z4 = {0.f, 0.f, 0.f, 0.f};

    for (int base = t0; base < t1 && base < L; base += 128) {
        __syncthreads();
        {   // stage E = exp(p) for [base, base+128) as f32
            const f32x4* p4 = (const f32x4*)(p + ((size_t)c * TT + base) * DD);
#pragma unroll
            for (int k2 = 0; k2 < 16; ++k2) {
                int idx = k2 * 128 + tid;
                f32x4 v = p4[idx];
                f32x4 ex;
                ex[0] = expf_fast(v[0]); ex[1] = expf_fast(v[1]);
                ex[2] = expf_fast(v[2]); ex[3] = expf_fast(v[3]);
                *((f32x4*)E + idx) = ex;
            }
        }
        __syncthreads();
        const int te = min(min(base + 128, t1), L);
        const int ts = (base == 0) ? 1 : base;      // t=0 folded into combine's u_0
        for (int t = ts; t < te; ++t) {
            const float* Er = E + (t - base) * 64;
            f32x4 acc[4][2];
#pragma unroll
            for (int mt = 0; mt < 4; ++mt)
#pragma unroll
                for (int nt = 0; nt < 2; ++nt) {
                    acc[mt][nt] = __builtin_amdgcn_mfma_f32_16x16x32_bf16(A[mt][0].v8, Bf[0][nt].v8, z4, 0, 0, 0);
                    acc[mt][nt] = __builtin_amdgcn_mfma_f32_16x16x32_bf16(A[mt][1].v8, Bf[1][nt].v8, acc[mt][nt], 0, 0, 0);
                }
            // sample max -> power-of-2 renorm (exact bookkeeping, all f32)
            float mx = fabsf(acc[0][0][0]);
#pragma unroll
            for (int mt = 0; mt < 4; ++mt)
#pragma unroll
                for (int nt = 0; nt < 2; ++nt) mx = fmaxf(mx, fabsf(acc[mt][nt][0]));
            DPPMAX(mx, 0x111, 0xF, 0xF); DPPMAX(mx, 0x112, 0xF, 0xF);
            DPPMAX(mx, 0x114, 0xF, 0xF); DPPMAX(mx, 0x118, 0xF, 0xF);
            DPPMAX(mx, 0x142, 0xA, 0xF); DPPMAX(mx, 0x143, 0xC, 0xF);
            int smx = __builtin_amdgcn_readlane(__float_as_int(mx), 63);
            int kk = ((smx >> 23) & 255) - 127;
            kk = kk < -110 ? -110 : (kk > 110 ? 110 : kk);
            sig += kk;
            // scale = 2^-kk * (1 + 2^-9): compensates bf16 truncation bias
            float sc = __int_as_float((unsigned)(127 - kk) << 23) * 1.001953125f;

            f32x4 es[4];
#pragma unroll
            for (int mt = 0; mt < 4; ++mt) {
                f32x4 ev = *(const f32x4*)(Er + 16 * mt + 4 * q);   // rows 16mt+4q+{0..3}
                ev[0] *= sc; ev[1] *= sc; ev[2] *= sc; ev[3] *= sc;
                es[mt] = ev;
            }
            // pack D -> next B (f32 scale, then 1 v_perm truncation per pair)
#pragma unroll
            for (int f = 0; f < 2; ++f)
#pragma unroll
                for (int nt = 0; nt < 2; ++nt)
#pragma unroll
                    for (int r = 0; r < 4; ++r) {
                        int mt = 2 * f + (r >> 1);
                        int e0 = 2 * (r & 1);
                        float x0 = acc[mt][nt][e0]     * es[mt][e0];
                        float x1 = acc[mt][nt][e0 + 1] * es[mt][e0 + 1];
                        Bf[f][nt].u[r] = __builtin_amdgcn_perm(__float_as_uint(x1), __float_as_uint(x0), 0x07060302u);
                    }
        }
    }

    // store H (row-major [64][64] bf16) + per-column-half log2 scale
    unsigned short* Hd = wsH + ((size_t)(c * C + ic)) * 4096;
#pragma unroll
    for (int kt2 = 0; kt2 < 2; ++kt2)
#pragma unroll
        for (int nt = 0; nt < 2; ++nt)
#pragma unroll
            for (int j = 0; j < 8; ++j) {
                int lam = 32 * kt2 + 16 * (j >> 2) + 4 * q + (j & 3);
                int col = 32 * w + 16 * nt + ml;
                Hd[lam * 64 + col] = (unsigned short)Bf[kt2][nt].s[j];
            }
    if (lane == 0) wsK[(c * C + ic) * 2 + w] = sig;
}

// ---------- kernel 3: per-chain combine + logZ - score ----------
__global__ __launch_bounds__(256) void crf_combine(
    const float* __restrict__ p, const unsigned short* __restrict__ wsH,
    const int* __restrict__ wsK, const float* __restrict__ wsS,
    float* __restrict__ out, int C)
{
    __shared__ float U[4][64];
    const int tid = threadIdx.x, w = tid >> 6, lane = tid & 63;
    const int c = blockIdx.x * 4 + w;

    U[w][lane] = expf_fast(p[(size_t)c * TT * DD + lane]);   // u_0 = exp(p_0)
    int Esc = 0;
    float o = 0.f;
    for (int ic = 0; ic < C; ++ic) {
        const uint4* h4 = (const uint4*)(wsH + ((size_t)(c * C + ic)) * 4096 + lane * 64);
        float alo = 0.f, ahi = 0.f;
#pragma unroll
        for (int i = 0; i < 8; ++i) {
            uint4 qv = h4[i];
            unsigned int uu[4] = {qv.x, qv.y, qv.z, qv.w};
#pragma unroll
            for (int k = 0; k < 4; ++k) {
                int cidx = i * 8 + k * 2;
                float h0 = __uint_as_float(uu[k] << 16);
                float h1 = __uint_as_float(uu[k] & 0xFFFF0000u);
                if (cidx < 32) {
                    alo = fmaf(h0, U[w][cidx], alo);
                    alo = fmaf(h1, U[w][cidx + 1], alo);
                } else {
                    ahi = fmaf(h0, U[w][cidx], ahi);
                    ahi = fmaf(h1, U[w][cidx + 1], ahi);
                }
            }
        }
        int s0 = wsK[(c * C + ic) * 2], s1v = wsK[(c * C + ic) * 2 + 1];
        int m = s0 > s1v ? s0 : s1v;
        o = ldexpf(alo, s0 - m) + ldexpf(ahi, s1v - m);
        Esc += m;
        float mo = o;
#pragma unroll
        for (int xm = 32; xm >= 1; xm >>= 1) mo = fmaxf(mo, __shfl_xor(mo, xm, 64));
        int k2 = ((__float_as_int(mo) >> 23) & 255) - 127;
        k2 = k2 < -120 ? -120 : (k2 > 120 ? 120 : k2);
        Esc += k2;
        o = ldexpf(o, -k2);
        U[w][lane] = o;
    }
    float sum = o;
#pragma unroll
    for (int xm = 32; xm >= 1; xm >>= 1) sum += __shfl_xor(sum, xm, 64);
    float logZ = C_LN2 * (__builtin_amdgcn_logf(sum) + (float)Esc);
    if (lane == 0) out[c] = logZ - wsS[c];
}

extern "C" void kernel_launch(void* const* d_in, const int* in_sizes, int n_in,
                              void* d_out, int out_size, void* d_ws, size_t ws_size,
                              hipStream_t stream) {
    const float* p  = (const float*)d_in[0];
    const int*   y  = (const int*)d_in[1];
    const int*   mk = (const int*)d_in[2];
    const float* tr = (const float*)d_in[3];
    float* out = (float*)d_out;

    int*   wsL = (int*)d_ws;
    float* wsS = (float*)((char*)d_ws + 1024);
    int*   wsK = (int*)((char*)d_ws + 2048);
    unsigned short* wsH = (unsigned short*)((char*)d_ws + 34816);

    int C = 16;
    if (ws_size < 34816 + (size_t)BB * 16 * 4096 * 2) C = 8;
    if (ws_size < 34816 + (size_t)BB * 8 * 4096 * 2)  C = 4;
    int S = TT / C;

    crf_score<<<dim3(BB), dim3(256), 0, stream>>>(p, y, mk, tr, wsL, wsS);
    crf_chunk<<<dim3(BB, C), dim3(128), 0, stream>>>(p, tr, wsL, wsH, wsK, C, S);
    crf_combine<<<dim3(BB / 4), dim3(256), 0, stream>>>(p, wsH, wsK, wsS, out, C);
}

// Round 6
// 476.023 us; speedup vs baseline: 3.4060x; 1.1310x over previous
//
#include <hip/hip_runtime.h>
#include <stdint.h>
#include <string.h>

#define BB 256
#define TT 2048
#define DD 64
#define C_L2E 1.44269504f
#define C_LN2 0.69314718f
// log2(1 + 2^-9): compensates bf16 truncation bias of the pack, folded into staging exp
#define C_BIAS 0.0028174f

typedef short sh8  __attribute__((ext_vector_type(8)));
typedef float f32x4 __attribute__((ext_vector_type(4)));

__device__ __forceinline__ float expf_fast(float x) { return __builtin_amdgcn_exp2f(x * C_L2E); }
__device__ __forceinline__ unsigned short bf16rne(float x) {
    unsigned int u = __float_as_uint(x);
    u += 0x7FFF + ((u >> 16) & 1u);
    return (unsigned short)(u >> 16);
}

#define DPPMAX(x, ctrl, rm, bm) { int _xi = __float_as_int(x);                              \
    int _yi = __builtin_amdgcn_update_dpp(_xi, _xi, ctrl, rm, bm, false);                   \
    x = fmaxf(x, __int_as_float(_yi)); }

// ---------- kernel 1: emission/transition scores, 8 segment-blocks per chain ----------
__global__ __launch_bounds__(256) void crf_score(
    const float* __restrict__ p, const int* __restrict__ y,
    const int* __restrict__ mask, const float* __restrict__ tr,
    float* __restrict__ wsS)
{
    __shared__ unsigned char labs[257];
    __shared__ float redf[4];
    const int c = blockIdx.y, t0 = blockIdx.x * 256;
    const int tid = threadIdx.x;
    const int t = t0 + tid;

    const int mv = mask[(size_t)c * TT + t];
    float s1 = 0.f, s2 = 0.f;
    if (mv == 0) {
        const int4* yt = (const int4*)y + ((size_t)c * TT + t) * 16;
        int lab = 0;
#pragma unroll
        for (int g = 0; g < 16; ++g) {
            int4 v = yt[g];
            if (v.x) lab = 4 * g;     if (v.y) lab = 4 * g + 1;
            if (v.z) lab = 4 * g + 2; if (v.w) lab = 4 * g + 3;
        }
        labs[tid] = (unsigned char)lab;
        s1 = p[((size_t)c * TT + t) * DD + lab];
    }
    if (tid == 0) {
        int tb = t0 + 256;
        if (tb < TT && mask[(size_t)c * TT + tb] == 0) {
            const int4* yt = (const int4*)y + ((size_t)c * TT + tb) * 16;
            int lab = 0;
#pragma unroll
            for (int g = 0; g < 16; ++g) {
                int4 v = yt[g];
                if (v.x) lab = 4 * g;     if (v.y) lab = 4 * g + 1;
                if (v.z) lab = 4 * g + 2; if (v.w) lab = 4 * g + 3;
            }
            labs[256] = (unsigned char)lab;
        }
    }
    __syncthreads();
    if (t + 1 < TT && mask[(size_t)c * TT + t + 1] == 0)   // pair (t,t+1) valid (prefix property)
        s2 = tr[(int)labs[tid] * DD + (int)labs[tid + 1]];

    float acc = s1 + s2;
#pragma unroll
    for (int xm = 32; xm >= 1; xm >>= 1) acc += __shfl_xor(acc, xm, 64);
    if ((tid & 63) == 0) redf[tid >> 6] = acc;
    __syncthreads();
    if (tid == 0) atomicAdd(&wsS[c], redf[0] + redf[1] + redf[2] + redf[3]);
}

// ---------- kernel 2: chunk transfer matrices H = prod_t diag(e_t) W^T  (bf16 MFMA) ----------
union BU { sh8 v8; unsigned int u[4]; unsigned short s[8]; };

__global__ __launch_bounds__(128, 3) void crf_chunk(
    const float* __restrict__ p, const float* __restrict__ tr,
    const int* __restrict__ mask,
    unsigned short* __restrict__ wsH, int* __restrict__ wsK,
    int C, int S)
{
    __shared__ float E[64 * 64];      // 16 KB: 64-step staging window
    __shared__ int cnt2[2];
    const int c = blockIdx.x, ic = blockIdx.y;
    const int t0 = ic * S, t1 = t0 + S;
    const int tid = threadIdx.x, w = tid >> 6, lane = tid & 63;
    const int q = lane >> 4, ml = lane & 15;

    // local valid count in [t0, t1) -> te (validity is a prefix)
    int cnt = 0;
    for (int tt = tid; tt < S; tt += 128) {
        int mv = mask[(size_t)c * TT + t0 + tt];
        cnt += __popcll(__ballot(mv == 0));
    }
    if (lane == 0) cnt2[w] = cnt;

    // A = W^T resident: A[mt][kt2].s[j] = bf16(exp(T[lam][16mt+ml]))
    BU A[4][2];
#pragma unroll
    for (int mt = 0; mt < 4; ++mt)
#pragma unroll
        for (int kt2 = 0; kt2 < 2; ++kt2)
#pragma unroll
            for (int j = 0; j < 8; ++j) {
                int lam = 32 * kt2 + 16 * (j >> 2) + 4 * q + (j & 3);
                A[mt][kt2].s[j] = (short)bf16rne(expf_fast(tr[lam * DD + 16 * mt + ml]));
            }

    // B init = identity
    BU Bf[2][2];
#pragma unroll
    for (int kt2 = 0; kt2 < 2; ++kt2)
#pragma unroll
        for (int nt = 0; nt < 2; ++nt)
#pragma unroll
            for (int j = 0; j < 8; ++j) {
                int lam = 32 * kt2 + 16 * (j >> 2) + 4 * q + (j & 3);
                int col = 32 * w + 16 * nt + ml;
                Bf[kt2][nt].s[j] = (short)((lam == col) ? 0x3F80 : 0);
            }

    __syncthreads();
    const int te = t0 + cnt2[0] + cnt2[1];

    int sig = 0;
    const f32x4 z4 = {0.f, 0.f, 0.f, 0.f};

    for (int base = t0; base < te; base += 64) {
        __syncthreads();
        {   // stage E = exp(p)*(1+2^-9) for [base, base+64) as f32
            const f32x4* p4 = (const f32x4*)(p + ((size_t)c * TT + base) * DD);
#pragma unroll
            for (int k2 = 0; k2 < 8; ++k2) {
                int idx = k2 * 128 + tid;
                f32x4 v = p4[idx];
                f32x4 ex;
                ex[0] = __builtin_amdgcn_exp2f(fmaf(v[0], C_L2E, C_BIAS));
                ex[1] = __builtin_amdgcn_exp2f(fmaf(v[1], C_L2E, C_BIAS));
                ex[2] = __builtin_amdgcn_exp2f(fmaf(v[2], C_L2E, C_BIAS));
                ex[3] = __builtin_amdgcn_exp2f(fmaf(v[3], C_L2E, C_BIAS));
                *((f32x4*)E + idx) = ex;
            }
        }
        __syncthreads();
        const int tend = (base + 64 < te) ? base + 64 : te;
        const int ts = (base == 0) ? 1 : base;      // t=0 folded into combine's u_0

        f32x4 er[4];
#pragma unroll
        for (int mt = 0; mt < 4; ++mt)
            er[mt] = *(const f32x4*)(E + (ts - base) * 64 + 16 * mt + 4 * q);

        for (int t = ts; t < tend; ++t) {
            f32x4 acc[4][2];
#pragma unroll
            for (int mt = 0; mt < 4; ++mt)
#pragma unroll
                for (int nt = 0; nt < 2; ++nt) {
                    acc[mt][nt] = __builtin_amdgcn_mfma_f32_16x16x32_bf16(A[mt][0].v8, Bf[0][nt].v8, z4, 0, 0, 0);
                    acc[mt][nt] = __builtin_amdgcn_mfma_f32_16x16x32_bf16(A[mt][1].v8, Bf[1][nt].v8, acc[mt][nt], 0, 0, 0);
                }
            // prefetch next step's e-rows while MFMA is in flight
            f32x4 ern[4];
            const bool more = (t + 1 < tend);
            if (more) {
#pragma unroll
                for (int mt = 0; mt < 4; ++mt)
                    ern[mt] = *(const f32x4*)(E + (t + 1 - base) * 64 + 16 * mt + 4 * q);
            }
            if ((t & 7) == 7) {   // renorm every 8th step (power of 2, exact bookkeeping)
                float mx = fabsf(acc[0][0][0]);
#pragma unroll
                for (int mt = 0; mt < 4; ++mt)
#pragma unroll
                    for (int nt = 0; nt < 2; ++nt) mx = fmaxf(mx, fabsf(acc[mt][nt][0]));
                DPPMAX(mx, 0x111, 0xF, 0xF); DPPMAX(mx, 0x112, 0xF, 0xF);
                DPPMAX(mx, 0x114, 0xF, 0xF); DPPMAX(mx, 0x118, 0xF, 0xF);
                DPPMAX(mx, 0x142, 0xA, 0xF); DPPMAX(mx, 0x143, 0xC, 0xF);
                int smx = __builtin_amdgcn_readlane(__float_as_int(mx), 63);
                int kk = ((smx >> 23) & 255) - 127 + 6;   // scale sampled max to ~2^-6
                kk = kk < -124 ? -124 : (kk > 124 ? 124 : kk);
                sig += kk;
                float sc = __int_as_float((unsigned)(127 - kk) << 23);
#pragma unroll
                for (int mt = 0; mt < 4; ++mt) {
                    er[mt][0] *= sc; er[mt][1] *= sc; er[mt][2] *= sc; er[mt][3] *= sc;
                }
            }
            // pack D -> next B with row-scale e (in-lane, lam order), 1 v_perm truncation per pair
#pragma unroll
            for (int f = 0; f < 2; ++f)
#pragma unroll
                for (int nt = 0; nt < 2; ++nt)
#pragma unroll
                    for (int r = 0; r < 4; ++r) {
                        int mt = 2 * f + (r >> 1);
                        int e0 = 2 * (r & 1);
                        float x0 = acc[mt][nt][e0]     * er[mt][e0];
                        float x1 = acc[mt][nt][e0 + 1] * er[mt][e0 + 1];
                        Bf[f][nt].u[r] = __builtin_amdgcn_perm(__float_as_uint(x1), __float_as_uint(x0), 0x07060302u);
                    }
            if (more) {
#pragma unroll
                for (int mt = 0; mt < 4; ++mt) er[mt] = ern[mt];
            }
        }
    }

    // store H (row-major [64][64] bf16) + per-column-half log2 scale
    unsigned short* Hd = wsH + ((size_t)(c * C + ic)) * 4096;
#pragma unroll
    for (int kt2 = 0; kt2 < 2; ++kt2)
#pragma unroll
        for (int nt = 0; nt < 2; ++nt)
#pragma unroll
            for (int j = 0; j < 8; ++j) {
                int lam = 32 * kt2 + 16 * (j >> 2) + 4 * q + (j & 3);
                int col = 32 * w + 16 * nt + ml;
                Hd[lam * 64 + col] = (unsigned short)Bf[kt2][nt].s[j];
            }
    if (lane == 0) wsK[(c * C + ic) * 2 + w] = sig;
}

// ---------- kernel 3: per-chain combine (prefetched) + logZ - score ----------
__global__ __launch_bounds__(256) void crf_combine(
    const float* __restrict__ p, const unsigned short* __restrict__ wsH,
    const int* __restrict__ wsK, const float* __restrict__ wsS,
    float* __restrict__ out, int C)
{
    __shared__ float U[4][64];
    const int tid = threadIdx.x, w = tid >> 6, lane = tid & 63;
    const int c = blockIdx.x * 4 + w;

    U[w][lane] = expf_fast(p[(size_t)c * TT * DD + lane]);   // u_0 = exp(p_0)
    int Esc = 0;
    float o = 0.f;

    uint4 h[8];
    {
        const uint4* hp = (const uint4*)(wsH + ((size_t)(c * C)) * 4096) + lane * 8;
#pragma unroll
        for (int i = 0; i < 8; ++i) h[i] = hp[i];
    }
    for (int ic = 0; ic < C; ++ic) {
        uint4 hn[8];
        if (ic + 1 < C) {
            const uint4* hp = (const uint4*)(wsH + ((size_t)(c * C + ic + 1)) * 4096) + lane * 8;
#pragma unroll
            for (int i = 0; i < 8; ++i) hn[i] = hp[i];
        }
        float al0 = 0.f, al1 = 0.f, ah0 = 0.f, ah1 = 0.f;
#pragma unroll
        for (int i = 0; i < 8; ++i) {
            unsigned int uu[4] = {h[i].x, h[i].y, h[i].z, h[i].w};
#pragma unroll
            for (int k = 0; k < 4; ++k) {
                int cidx = i * 8 + k * 2;
                float h0 = __uint_as_float(uu[k] << 16);
                float h1 = __uint_as_float(uu[k] & 0xFFFF0000u);
                if (i < 4) {
                    if (k & 1) { al1 = fmaf(h0, U[w][cidx], al1); al1 = fmaf(h1, U[w][cidx + 1], al1); }
                    else       { al0 = fmaf(h0, U[w][cidx], al0); al0 = fmaf(h1, U[w][cidx + 1], al0); }
                } else {
                    if (k & 1) { ah1 = fmaf(h0, U[w][cidx], ah1); ah1 = fmaf(h1, U[w][cidx + 1], ah1); }
                    else       { ah0 = fmaf(h0, U[w][cidx], ah0); ah0 = fmaf(h1, U[w][cidx + 1], ah0); }
                }
            }
        }
        float alo = al0 + al1, ahi = ah0 + ah1;
        int s0 = wsK[(c * C + ic) * 2], s1v = wsK[(c * C + ic) * 2 + 1];
        int m = s0 > s1v ? s0 : s1v;
        o = ldexpf(alo, s0 - m) + ldexpf(ahi, s1v - m);
        Esc += m;
        float mo = o;
#pragma unroll
        for (int xm = 32; xm >= 1; xm >>= 1) mo = fmaxf(mo, __shfl_xor(mo, xm, 64));
        int k2 = ((__float_as_int(mo) >> 23) & 255) - 127;
        k2 = k2 < -120 ? -120 : (k2 > 120 ? 120 : k2);
        Esc += k2;
        o = ldexpf(o, -k2);
        U[w][lane] = o;
#pragma unroll
        for (int i = 0; i < 8; ++i) h[i] = hn[i];
    }
    float sum = o;
#pragma unroll
    for (int xm = 32; xm >= 1; xm >>= 1) sum += __shfl_xor(sum, xm, 64);
    float logZ = C_LN2 * (__builtin_amdgcn_logf(sum) + (float)Esc);
    if (lane == 0) out[c] = logZ - wsS[c];
}

extern "C" void kernel_launch(void* const* d_in, const int* in_sizes, int n_in,
                              void* d_out, int out_size, void* d_ws, size_t ws_size,
                              hipStream_t stream) {
    const float* p  = (const float*)d_in[0];
    const int*   y  = (const int*)d_in[1];
    const int*   mk = (const int*)d_in[2];
    const float* tr = (const float*)d_in[3];
    float* out = (float*)d_out;

    float* wsS = (float*)d_ws;                               // 1 KB
    int*   wsK = (int*)((char*)d_ws + 1024);                 // 32 KB
    unsigned short* wsH = (unsigned short*)((char*)d_ws + 33792);

    int C = 16;
    if (ws_size < 33792 + (size_t)BB * 16 * 4096 * 2) C = 8;
    if (ws_size < 33792 + (size_t)BB * 8 * 4096 * 2)  C = 4;
    int S = TT / C;

    hipMemsetAsync(wsS, 0, BB * sizeof(float), stream);
    crf_score<<<dim3(8, BB), dim3(256), 0, stream>>>(p, y, mk, tr, wsS);
    crf_chunk<<<dim3(BB, C), dim3(128), 0, stream>>>(p, tr, mk, wsH, wsK, C, S);
    crf_combine<<<dim3(BB / 4), dim3(256), 0, stream>>>(p, wsH, wsK, wsS, out, C);
}